// Round 1
// baseline (553.550 us; speedup 1.0000x reference)
//
#include <hip/hip_runtime.h>
#include <math.h>

#define NN 50000
#define EE 600000
#define DD 128
#define KAPPA_C 0.95f
#define EPS_C 1e-5f
#define SCAN_BLK 1024
#define NB_SCAN ((NN + SCAN_BLK - 1) / SCAN_BLK)   // 49

// ---------------- W = Fm^T Fm, plus sum of squares ----------------
__global__ __launch_bounds__(128) void wmat_kernel(const float* __restrict__ Fm,
                                                   float* __restrict__ W,
                                                   float* __restrict__ ssq) {
    const int i = blockIdx.x;     // output row
    const int j = threadIdx.x;    // output col
    float acc = 0.f;
    #pragma unroll 8
    for (int k = 0; k < 128; ++k)
        acc += Fm[k * 128 + i] * Fm[k * 128 + j];   // [k][i] uniform (scalar), [k][j] coalesced
    W[i * 128 + j] = acc;
    __shared__ float red[128];
    red[j] = acc * acc;
    __syncthreads();
    for (int o = 64; o > 0; o >>= 1) {
        if (j < o) red[j] += red[j + o];
        __syncthreads();
    }
    if (j == 0) atomicAdd(ssq, red[0]);
}

__global__ void wscale_kernel(float* __restrict__ W, const float* __restrict__ ssq) {
    int idx = blockIdx.x * blockDim.x + threadIdx.x;
    if (idx < 128 * 128) {
        float n = sqrtf(*ssq);
        if (n > 1.0f) W[idx] = W[idx] / (n + EPS_C);
    }
}

// ---------------- CSR build: histogram -> scan -> fill ----------------
__global__ void hist_kernel(const int* __restrict__ dst, int* __restrict__ counts) {
    int e = blockIdx.x * blockDim.x + threadIdx.x;
    if (e < EE) atomicAdd(&counts[dst[e]], 1);
}

__global__ __launch_bounds__(SCAN_BLK) void scan_blocks(const int* __restrict__ counts,
                                                        int* __restrict__ rs,
                                                        int* __restrict__ bsum) {
    __shared__ int sd[SCAN_BLK];
    int tid = threadIdx.x;
    int gid = blockIdx.x * SCAN_BLK + tid;
    int v = (gid < NN) ? counts[gid] : 0;
    sd[tid] = v;
    __syncthreads();
    for (int o = 1; o < SCAN_BLK; o <<= 1) {
        int t = (tid >= o) ? sd[tid - o] : 0;
        __syncthreads();
        sd[tid] += t;
        __syncthreads();
    }
    if (gid < NN) rs[gid] = sd[tid] - v;            // exclusive within block
    if (tid == SCAN_BLK - 1) bsum[blockIdx.x] = sd[tid];
}

__global__ void scan_sums(int* __restrict__ bsum, int* __restrict__ rs) {
    if (threadIdx.x == 0 && blockIdx.x == 0) {
        int run = 0;
        for (int i = 0; i < NB_SCAN; ++i) { int t = bsum[i]; bsum[i] = run; run += t; }
        rs[NN] = EE;
    }
}

__global__ __launch_bounds__(SCAN_BLK) void scan_add(int* __restrict__ rs,
                                                     const int* __restrict__ bsum) {
    int gid = blockIdx.x * SCAN_BLK + threadIdx.x;
    if (gid < NN) rs[gid] += bsum[blockIdx.x];
}

__global__ void fill_kernel(const int* __restrict__ src, const int* __restrict__ dst,
                            const float* __restrict__ w, const int* __restrict__ rs,
                            int* __restrict__ cursor, int* __restrict__ csr_src,
                            float* __restrict__ csr_w) {
    int e = blockIdx.x * blockDim.x + threadIdx.x;
    if (e < EE) {
        int d = dst[e];
        int pos = atomicAdd(&cursor[d], 1);
        int idx = rs[d] + pos;
        csr_src[idx] = src[e];
        csr_w[idx] = w[e];
    }
}

// ---------------- GEMM: out[N x 128] = alpha * (X @ M) (+ out) ----------------
// block = 128 threads (c = tid), 32 rows per block.
// X-row reads are threadIdx-uniform -> scalar loads; M column chunk in VGPRs.
template <bool FULL>
__global__ __launch_bounds__(128) void gemm128(const float* __restrict__ X,
                                               const float* __restrict__ M,
                                               float* __restrict__ out,
                                               int nrows, float alpha, int accum) {
    const int c = threadIdx.x;
    const int r0 = blockIdx.x * 32;
    int rows = nrows - r0;
    if (rows > 32) rows = 32;
    float acc[32];
    #pragma unroll
    for (int r = 0; r < 32; ++r) acc[r] = 0.f;

    for (int kc = 0; kc < 128; kc += 16) {
        float w[16];
        #pragma unroll
        for (int kk = 0; kk < 16; ++kk) w[kk] = M[(kc + kk) * 128 + c];
        #pragma unroll
        for (int r = 0; r < 32; ++r) {
            if (FULL || r < rows) {
                const float* xp = X + (size_t)(r0 + r) * 128 + kc;
                float4 a0 = *(const float4*)(xp + 0);
                float4 a1 = *(const float4*)(xp + 4);
                float4 a2 = *(const float4*)(xp + 8);
                float4 a3 = *(const float4*)(xp + 12);
                acc[r] += a0.x * w[0] + a0.y * w[1] + a0.z * w[2] + a0.w * w[3]
                        + a1.x * w[4] + a1.y * w[5] + a1.z * w[6] + a1.w * w[7]
                        + a2.x * w[8] + a2.y * w[9] + a2.z * w[10] + a2.w * w[11]
                        + a3.x * w[12] + a3.y * w[13] + a3.z * w[14] + a3.w * w[15];
            }
        }
    }
    #pragma unroll
    for (int r = 0; r < 32; ++r) {
        if (FULL || r < rows) {
            size_t o = (size_t)(r0 + r) * 128 + c;
            float v = alpha * acc[r];
            if (accum) v += out[o];
            out[o] = v;
        }
    }
}

// ---------------- SpMM (CSR by dst): out[d] = sum_e w_e * h[src_e]  ----------------
// 32 lanes per dst row, float4 per lane. mode: 0 plain, 1 +bias relu, 2 +bias
__global__ __launch_bounds__(256) void spmm_kernel(const float* __restrict__ h,
                                                   const int* __restrict__ rs,
                                                   const int* __restrict__ csr_src,
                                                   const float* __restrict__ csr_w,
                                                   const float* __restrict__ bias,
                                                   float* __restrict__ out, int mode) {
    int node = blockIdx.x * 8 + (threadIdx.x >> 5);
    int lane = threadIdx.x & 31;
    if (node >= NN) return;
    int e = rs[node];
    const int re = rs[node + 1];
    float4 acc = make_float4(0.f, 0.f, 0.f, 0.f);
    for (; e + 1 < re; e += 2) {
        int s0 = csr_src[e];
        int s1 = csr_src[e + 1];
        float w0 = csr_w[e];
        float w1 = csr_w[e + 1];
        float4 v0 = *(const float4*)(h + (size_t)s0 * 128 + lane * 4);
        float4 v1 = *(const float4*)(h + (size_t)s1 * 128 + lane * 4);
        acc.x += w0 * v0.x; acc.y += w0 * v0.y; acc.z += w0 * v0.z; acc.w += w0 * v0.w;
        acc.x += w1 * v1.x; acc.y += w1 * v1.y; acc.z += w1 * v1.z; acc.w += w1 * v1.w;
    }
    if (e < re) {
        int s0 = csr_src[e];
        float w0 = csr_w[e];
        float4 v0 = *(const float4*)(h + (size_t)s0 * 128 + lane * 4);
        acc.x += w0 * v0.x; acc.y += w0 * v0.y; acc.z += w0 * v0.z; acc.w += w0 * v0.w;
    }
    if (mode != 0) {
        float4 b = *(const float4*)(bias + lane * 4);
        acc.x += b.x; acc.y += b.y; acc.z += b.z; acc.w += b.w;
        if (mode == 1) {
            acc.x = fmaxf(acc.x, 0.f); acc.y = fmaxf(acc.y, 0.f);
            acc.z = fmaxf(acc.z, 0.f); acc.w = fmaxf(acc.w, 0.f);
        }
    }
    *(float4*)(out + (size_t)node * 128 + lane * 4) = acc;
}

static inline size_t align_up(size_t x, size_t a) { return (x + a - 1) / a * a; }

extern "C" void kernel_launch(void* const* d_in, const int* in_sizes, int n_in,
                              void* d_out, int out_size, void* d_ws, size_t ws_size,
                              hipStream_t stream) {
    const float* x   = (const float*)d_in[0];
    const int*   esrc = (const int*)d_in[1];
    const int*   edst = (const int*)d_in[2];
    const float* ew  = (const float*)d_in[3];
    const float* W1  = (const float*)d_in[4];
    const float* b1  = (const float*)d_in[5];
    const float* W2  = (const float*)d_in[6];
    const float* b2  = (const float*)d_in[7];
    const float* Fm  = (const float*)d_in[8];
    const float* emb = (const float*)d_in[9];
    float* out = (float*)d_out;

    char* ws = (char*)d_ws;
    size_t off = 0;
    auto alloc = [&](size_t bytes) -> void* {
        void* p = ws + off;
        off = align_up(off + bytes, 256);
        return p;
    };
    float* A      = (float*)alloc((size_t)NN * DD * 4);   // 25.6 MB scratch feature buffer
    float* Wmat   = (float*)alloc(128 * 128 * 4);
    int*   counts = (int*)alloc((size_t)NN * 4);
    int*   cursor = (int*)alloc((size_t)NN * 4);
    float* ssq    = (float*)alloc(256);
    int*   rs     = (int*)alloc((size_t)(NN + 1) * 4);
    int*   bsum   = (int*)alloc(64 * 4);
    int*   csrc   = (int*)alloc((size_t)EE * 4);
    float* cw     = (float*)alloc((size_t)EE * 4);
    if (off > ws_size) return;  // workspace too small -> fail visibly

    // zero the contiguous [counts | cursor | ssq] region
    size_t zero_bytes = (size_t)((char*)ssq - (char*)counts) + 256;
    hipMemsetAsync(counts, 0, zero_bytes, stream);

    // projection matrix W = norm(Fm^T Fm)
    wmat_kernel<<<128, 128, 0, stream>>>(Fm, Wmat, ssq);
    wscale_kernel<<<64, 256, 0, stream>>>(Wmat, ssq);

    // CSR build (by dst)
    hist_kernel<<<(EE + 255) / 256, 256, 0, stream>>>(edst, counts);
    scan_blocks<<<NB_SCAN, SCAN_BLK, 0, stream>>>(counts, rs, bsum);
    scan_sums<<<1, 64, 0, stream>>>(bsum, rs);
    scan_add<<<NB_SCAN, SCAN_BLK, 0, stream>>>(rs, bsum);
    fill_kernel<<<(EE + 255) / 256, 256, 0, stream>>>(esrc, edst, ew, rs, cursor, csrc, cw);

    const int gemm_grid = (NN + 31) / 32;   // 1563 (last block partial)
    const int spmm_grid = (NN + 7) / 8;     // 6250

    // h1 = x @ W1
    gemm128<false><<<gemm_grid, 128, 0, stream>>>(x, W1, A, NN, 1.0f, 0);
    // h = relu(spmm(h1) + b1)  -> d_out
    spmm_kernel<<<spmm_grid, 256, 0, stream>>>(A, rs, csrc, cw, b1, out, 1);
    // h2 = h @ W2 -> A
    gemm128<false><<<gemm_grid, 128, 0, stream>>>(out, W2, A, NN, 1.0f, 0);
    // base = spmm(h2) + b2 -> d_out
    spmm_kernel<<<spmm_grid, 256, 0, stream>>>(A, rs, csrc, cw, b2, out, 2);
    // s3 = spmm(emb) -> A
    spmm_kernel<<<spmm_grid, 256, 0, stream>>>(emb, rs, csrc, cw, nullptr, A, 0);
    // out = KAPPA * (s3 @ W) + base
    gemm128<false><<<gemm_grid, 128, 0, stream>>>(A, Wmat, out, NN, KAPPA_C, 1);
}

// Round 2
// 333.070 us; speedup vs baseline: 1.6620x; 1.6620x over previous
//
#include <hip/hip_runtime.h>
#include <math.h>

#define NN 50000
#define EE 600000
#define DD 128
#define KAPPA_C 0.95f
#define EPS_C 1e-5f
#define SCAN_BLK 1024
#define NB_SCAN ((NN + SCAN_BLK - 1) / SCAN_BLK)   // 49

typedef short s16x8 __attribute__((ext_vector_type(8)));   // 8 bf16 (4 VGPRs)
typedef float f32x4 __attribute__((ext_vector_type(4)));

// float -> bf16 bits, round-to-nearest-even
__device__ __forceinline__ unsigned short f2bf(float f) {
    union { float f; unsigned int u; } v;
    v.f = f;
    unsigned int r = v.u + 0x7fffu + ((v.u >> 16) & 1u);
    return (unsigned short)(r >> 16);
}
__device__ __forceinline__ float bf2f(unsigned short b) {
    union { unsigned int u; float f; } v;
    v.u = ((unsigned int)b) << 16;
    return v.f;
}

// ---------------- W = Fm^T Fm, plus sum of squares ----------------
__global__ __launch_bounds__(128) void wmat_kernel(const float* __restrict__ Fm,
                                                   float* __restrict__ W,
                                                   float* __restrict__ ssq) {
    const int i = blockIdx.x;     // output row
    const int j = threadIdx.x;    // output col
    float acc = 0.f;
    #pragma unroll 8
    for (int k = 0; k < 128; ++k)
        acc += Fm[k * 128 + i] * Fm[k * 128 + j];
    W[i * 128 + j] = acc;
    __shared__ float red[128];
    red[j] = acc * acc;
    __syncthreads();
    for (int o = 64; o > 0; o >>= 1) {
        if (j < o) red[j] += red[j + o];
        __syncthreads();
    }
    if (j == 0) atomicAdd(ssq, red[0]);
}

__global__ void wscale_kernel(float* __restrict__ W, const float* __restrict__ ssq) {
    int idx = blockIdx.x * blockDim.x + threadIdx.x;
    if (idx < 128 * 128) {
        float n = sqrtf(*ssq);
        if (n > 1.0f) W[idx] = W[idx] / (n + EPS_C);
    }
}

// ---------------- CSR build: histogram -> scan -> fill ----------------
__global__ void hist_kernel(const int* __restrict__ dst, int* __restrict__ counts) {
    int e = blockIdx.x * blockDim.x + threadIdx.x;
    if (e < EE) atomicAdd(&counts[dst[e]], 1);
}

__global__ __launch_bounds__(SCAN_BLK) void scan_blocks(const int* __restrict__ counts,
                                                        int* __restrict__ rs,
                                                        int* __restrict__ bsum) {
    __shared__ int sd[SCAN_BLK];
    int tid = threadIdx.x;
    int gid = blockIdx.x * SCAN_BLK + tid;
    int v = (gid < NN) ? counts[gid] : 0;
    sd[tid] = v;
    __syncthreads();
    for (int o = 1; o < SCAN_BLK; o <<= 1) {
        int t = (tid >= o) ? sd[tid - o] : 0;
        __syncthreads();
        sd[tid] += t;
        __syncthreads();
    }
    if (gid < NN) rs[gid] = sd[tid] - v;
    if (tid == SCAN_BLK - 1) bsum[blockIdx.x] = sd[tid];
}

__global__ void scan_sums(int* __restrict__ bsum, int* __restrict__ rs) {
    if (threadIdx.x == 0 && blockIdx.x == 0) {
        int run = 0;
        for (int i = 0; i < NB_SCAN; ++i) { int t = bsum[i]; bsum[i] = run; run += t; }
        rs[NN] = EE;
    }
}

__global__ __launch_bounds__(SCAN_BLK) void scan_add(int* __restrict__ rs,
                                                     const int* __restrict__ bsum) {
    int gid = blockIdx.x * SCAN_BLK + threadIdx.x;
    if (gid < NN) rs[gid] += bsum[blockIdx.x];
}

__global__ void fill_kernel(const int* __restrict__ src, const int* __restrict__ dst,
                            const float* __restrict__ w, const int* __restrict__ rs,
                            int* __restrict__ cursor, int* __restrict__ csr_src,
                            float* __restrict__ csr_w) {
    int e = blockIdx.x * blockDim.x + threadIdx.x;
    if (e < EE) {
        int d = dst[e];
        int pos = atomicAdd(&cursor[d], 1);
        int idx = rs[d] + pos;
        csr_src[idx] = src[e];
        csr_w[idx] = w[e];
    }
}

// ---------------- conversions ----------------
// f32 [n4*4] -> bf16 bits, vectorized 4/thread
__global__ __launch_bounds__(256) void convx_kernel(const float* __restrict__ in,
                                                    unsigned short* __restrict__ outh,
                                                    int n4) {
    int i = blockIdx.x * 256 + threadIdx.x;
    if (i < n4) {
        float4 v = ((const float4*)in)[i];
        ushort4 h;
        h.x = f2bf(v.x); h.y = f2bf(v.y); h.z = f2bf(v.z); h.w = f2bf(v.w);
        ((ushort4*)outh)[i] = h;
    }
}

// M f32 [128x128] -> transposed split bf16: Mth[n][k], Mtl[n][k]
__global__ __launch_bounds__(256) void convm_kernel(const float* __restrict__ M,
                                                    unsigned short* __restrict__ Mth,
                                                    unsigned short* __restrict__ Mtl) {
    int id = blockIdx.x * 256 + threadIdx.x;     // 0..16383
    int k = id >> 7, n = id & 127;
    float v = M[id];
    unsigned short h = f2bf(v);
    float r = v - bf2f(h);
    Mth[n * 128 + k] = h;
    Mtl[n * 128 + k] = f2bf(r);
}

// ---------------- MFMA GEMM: out[N x 128] f32 = alpha * Xh @ (Mth + Mtl)^T' (+ out) ----------------
// Xh: bf16 bits [N x 128] row-major. Mth/Mtl: bf16 bits [128 x 128], Mt[n][k] = M[k][n].
// block = 256 threads = 4 waves; block tile 64 rows x 128 cols; wave tile 32 x 64.
__global__ __launch_bounds__(256) void gemm_mfma(const unsigned short* __restrict__ Xh,
                                                 const unsigned short* __restrict__ Mth,
                                                 const unsigned short* __restrict__ Mtl,
                                                 float* __restrict__ out,
                                                 int nrows, float alpha, int accum) {
    const int wave = threadIdx.x >> 6;            // 0..3
    const int lane = threadIdx.x & 63;
    const int row0 = blockIdx.x * 64 + (wave >> 1) * 32;
    const int col0 = (wave & 1) * 64;
    const int lr = lane & 15;                     // row/col within 16-subtile
    const int kg = lane >> 4;                     // k-group 0..3

    f32x4 acc[2][4];
    #pragma unroll
    for (int m = 0; m < 2; ++m)
        #pragma unroll
        for (int n = 0; n < 4; ++n)
            acc[m][n] = (f32x4){0.f, 0.f, 0.f, 0.f};

    #pragma unroll
    for (int k0 = 0; k0 < 128; k0 += 32) {
        s16x8 a[2];
        #pragma unroll
        for (int m = 0; m < 2; ++m) {
            int r = row0 + m * 16 + lr;
            if (r >= nrows) r = nrows - 1;        // clamp; garbage rows not stored
            a[m] = *(const s16x8*)(Xh + (size_t)r * 128 + k0 + kg * 8);
        }
        #pragma unroll
        for (int n = 0; n < 4; ++n) {
            const int c = col0 + n * 16 + lr;
            s16x8 bh = *(const s16x8*)(Mth + c * 128 + k0 + kg * 8);
            s16x8 bl = *(const s16x8*)(Mtl + c * 128 + k0 + kg * 8);
            #pragma unroll
            for (int m = 0; m < 2; ++m) {
                acc[m][n] = __builtin_amdgcn_mfma_f32_16x16x32_bf16(a[m], bh, acc[m][n], 0, 0, 0);
                acc[m][n] = __builtin_amdgcn_mfma_f32_16x16x32_bf16(a[m], bl, acc[m][n], 0, 0, 0);
            }
        }
    }

    // D layout: col = lane&15, row = (lane>>4)*4 + j   [m89]
    #pragma unroll
    for (int m = 0; m < 2; ++m) {
        #pragma unroll
        for (int n = 0; n < 4; ++n) {
            #pragma unroll
            for (int j = 0; j < 4; ++j) {
                int r = row0 + m * 16 + kg * 4 + j;
                int c = col0 + n * 16 + lr;
                if (r < nrows) {
                    size_t o = (size_t)r * 128 + c;
                    float v = alpha * acc[m][n][j];
                    if (accum) v += out[o];
                    out[o] = v;
                }
            }
        }
    }
}

// ---------------- SpMM (CSR by dst): out[d] = sum_e w_e * h[src_e]  ----------------
__global__ __launch_bounds__(256) void spmm_kernel(const float* __restrict__ h,
                                                   const int* __restrict__ rs,
                                                   const int* __restrict__ csr_src,
                                                   const float* __restrict__ csr_w,
                                                   const float* __restrict__ bias,
                                                   float* __restrict__ out, int mode) {
    int node = blockIdx.x * 8 + (threadIdx.x >> 5);
    int lane = threadIdx.x & 31;
    if (node >= NN) return;
    int e = rs[node];
    const int re = rs[node + 1];
    float4 acc = make_float4(0.f, 0.f, 0.f, 0.f);
    for (; e + 1 < re; e += 2) {
        int s0 = csr_src[e];
        int s1 = csr_src[e + 1];
        float w0 = csr_w[e];
        float w1 = csr_w[e + 1];
        float4 v0 = *(const float4*)(h + (size_t)s0 * 128 + lane * 4);
        float4 v1 = *(const float4*)(h + (size_t)s1 * 128 + lane * 4);
        acc.x += w0 * v0.x; acc.y += w0 * v0.y; acc.z += w0 * v0.z; acc.w += w0 * v0.w;
        acc.x += w1 * v1.x; acc.y += w1 * v1.y; acc.z += w1 * v1.z; acc.w += w1 * v1.w;
    }
    if (e < re) {
        int s0 = csr_src[e];
        float w0 = csr_w[e];
        float4 v0 = *(const float4*)(h + (size_t)s0 * 128 + lane * 4);
        acc.x += w0 * v0.x; acc.y += w0 * v0.y; acc.z += w0 * v0.z; acc.w += w0 * v0.w;
    }
    if (mode != 0) {
        float4 b = *(const float4*)(bias + lane * 4);
        acc.x += b.x; acc.y += b.y; acc.z += b.z; acc.w += b.w;
        if (mode == 1) {
            acc.x = fmaxf(acc.x, 0.f); acc.y = fmaxf(acc.y, 0.f);
            acc.z = fmaxf(acc.z, 0.f); acc.w = fmaxf(acc.w, 0.f);
        }
    }
    *(float4*)(out + (size_t)node * 128 + lane * 4) = acc;
}

static inline size_t align_up(size_t x, size_t a) { return (x + a - 1) / a * a; }

extern "C" void kernel_launch(void* const* d_in, const int* in_sizes, int n_in,
                              void* d_out, int out_size, void* d_ws, size_t ws_size,
                              hipStream_t stream) {
    const float* x   = (const float*)d_in[0];
    const int*   esrc = (const int*)d_in[1];
    const int*   edst = (const int*)d_in[2];
    const float* ew  = (const float*)d_in[3];
    const float* W1  = (const float*)d_in[4];
    const float* b1  = (const float*)d_in[5];
    const float* W2  = (const float*)d_in[6];
    const float* b2  = (const float*)d_in[7];
    const float* Fm  = (const float*)d_in[8];
    const float* emb = (const float*)d_in[9];
    float* out = (float*)d_out;

    char* ws = (char*)d_ws;
    size_t off = 0;
    auto alloc = [&](size_t bytes) -> void* {
        void* p = ws + off;
        off = align_up(off + bytes, 256);
        return p;
    };
    float* A      = (float*)alloc((size_t)NN * DD * 4);       // 25.6 MB f32 feature scratch
    float* Wmat   = (float*)alloc(128 * 128 * 4);
    int*   counts = (int*)alloc((size_t)NN * 4);
    int*   cursor = (int*)alloc((size_t)NN * 4);
    float* ssq    = (float*)alloc(256);
    int*   rs     = (int*)alloc((size_t)(NN + 1) * 4);
    int*   bsum   = (int*)alloc(64 * 4);
    int*   csrc   = (int*)alloc((size_t)EE * 4);
    float* cw     = (float*)alloc((size_t)EE * 4);
    unsigned short* Xh   = (unsigned short*)alloc((size_t)NN * DD * 2);  // 12.8 MB bf16 staging
    unsigned short* W1th = (unsigned short*)alloc(128 * 128 * 2);
    unsigned short* W1tl = (unsigned short*)alloc(128 * 128 * 2);
    unsigned short* W2th = (unsigned short*)alloc(128 * 128 * 2);
    unsigned short* W2tl = (unsigned short*)alloc(128 * 128 * 2);
    unsigned short* Wmth = (unsigned short*)alloc(128 * 128 * 2);
    unsigned short* Wmtl = (unsigned short*)alloc(128 * 128 * 2);
    if (off > ws_size) return;  // workspace too small -> fail visibly

    // zero [counts | cursor | ssq]
    size_t zero_bytes = (size_t)((char*)ssq - (char*)counts) + 256;
    hipMemsetAsync(counts, 0, zero_bytes, stream);

    // projection matrix W = norm(Fm^T Fm); weight conversions
    wmat_kernel<<<128, 128, 0, stream>>>(Fm, Wmat, ssq);
    wscale_kernel<<<64, 256, 0, stream>>>(Wmat, ssq);
    convm_kernel<<<64, 256, 0, stream>>>(W1, W1th, W1tl);
    convm_kernel<<<64, 256, 0, stream>>>(W2, W2th, W2tl);
    convm_kernel<<<64, 256, 0, stream>>>(Wmat, Wmth, Wmtl);

    // CSR build (by dst)
    hist_kernel<<<(EE + 255) / 256, 256, 0, stream>>>(edst, counts);
    scan_blocks<<<NB_SCAN, SCAN_BLK, 0, stream>>>(counts, rs, bsum);
    scan_sums<<<1, 64, 0, stream>>>(bsum, rs);
    scan_add<<<NB_SCAN, SCAN_BLK, 0, stream>>>(rs, bsum);
    fill_kernel<<<(EE + 255) / 256, 256, 0, stream>>>(esrc, edst, ew, rs, cursor, csrc, cw);

    const int n4 = NN * DD / 4;                 // 1.6M float4 groups
    const int conv_grid = (n4 + 255) / 256;     // 6250
    const int gemm_grid = (NN + 63) / 64;       // 782
    const int spmm_grid = (NN + 7) / 8;         // 6250

    // h1 = x @ W1 -> A
    convx_kernel<<<conv_grid, 256, 0, stream>>>(x, Xh, n4);
    gemm_mfma<<<gemm_grid, 256, 0, stream>>>(Xh, W1th, W1tl, A, NN, 1.0f, 0);
    // h = relu(spmm(h1) + b1) -> out
    spmm_kernel<<<spmm_grid, 256, 0, stream>>>(A, rs, csrc, cw, b1, out, 1);
    // h2 = h @ W2 -> A
    convx_kernel<<<conv_grid, 256, 0, stream>>>(out, Xh, n4);
    gemm_mfma<<<gemm_grid, 256, 0, stream>>>(Xh, W2th, W2tl, A, NN, 1.0f, 0);
    // base = spmm(h2) + b2 -> out
    spmm_kernel<<<spmm_grid, 256, 0, stream>>>(A, rs, csrc, cw, b2, out, 2);
    // s3 = spmm(emb) -> A
    spmm_kernel<<<spmm_grid, 256, 0, stream>>>(emb, rs, csrc, cw, nullptr, A, 0);
    // out = KAPPA * (s3 @ Wmat) + base
    convx_kernel<<<conv_grid, 256, 0, stream>>>(A, Xh, n4);
    gemm_mfma<<<gemm_grid, 256, 0, stream>>>(Xh, Wmth, Wmtl, out, NN, KAPPA_C, 1);
}

// Round 3
// 275.557 us; speedup vs baseline: 2.0088x; 1.2087x over previous
//
#include <hip/hip_runtime.h>
#include <math.h>

#define NN 50000
#define EE 600000
#define DD 128
#define KAPPA_C 0.95f
#define EPS_C 1e-5f
#define SCAN_BLK 1024
#define NB_SCAN ((NN + SCAN_BLK - 1) / SCAN_BLK)   // 49

typedef short s16x8 __attribute__((ext_vector_type(8)));   // 8 bf16 (4 VGPRs)
typedef float f32x4 __attribute__((ext_vector_type(4)));

// float -> bf16 bits, round-to-nearest-even
__device__ __forceinline__ unsigned short f2bf(float f) {
    union { float f; unsigned int u; } v;
    v.f = f;
    unsigned int r = v.u + 0x7fffu + ((v.u >> 16) & 1u);
    return (unsigned short)(r >> 16);
}
__device__ __forceinline__ float bf2f(unsigned short b) {
    union { unsigned int u; float f; } v;
    v.u = ((unsigned int)b) << 16;
    return v.f;
}

// ---------------- W = Fm^T Fm, plus sum of squares ----------------
__global__ __launch_bounds__(128) void wmat_kernel(const float* __restrict__ Fm,
                                                   float* __restrict__ W,
                                                   float* __restrict__ ssq) {
    const int i = blockIdx.x;     // output row
    const int j = threadIdx.x;    // output col
    float acc = 0.f;
    #pragma unroll 8
    for (int k = 0; k < 128; ++k)
        acc += Fm[k * 128 + i] * Fm[k * 128 + j];
    W[i * 128 + j] = acc;
    __shared__ float red[128];
    red[j] = acc * acc;
    __syncthreads();
    for (int o = 64; o > 0; o >>= 1) {
        if (j < o) red[j] += red[j + o];
        __syncthreads();
    }
    if (j == 0) atomicAdd(ssq, red[0]);
}

// fused: scale Wmat by 1/(norm+eps) if norm>1, emit transposed split-bf16
__global__ __launch_bounds__(256) void wsplit_kernel(const float* __restrict__ Wmat,
                                                     const float* __restrict__ ssq,
                                                     unsigned short* __restrict__ Mth,
                                                     unsigned short* __restrict__ Mtl) {
    int id = blockIdx.x * 256 + threadIdx.x;     // 0..16383
    float n = sqrtf(*ssq);
    float s = (n > 1.0f) ? 1.0f / (n + EPS_C) : 1.0f;
    float v = Wmat[id] * s;
    int k = id >> 7, c = id & 127;
    unsigned short h = f2bf(v);
    Mth[c * 128 + k] = h;
    Mtl[c * 128 + k] = f2bf(v - bf2f(h));
}

// W1 and W2 -> transposed split bf16, one dispatch (blockIdx<64 -> W1)
__global__ __launch_bounds__(256) void convm2_kernel(const float* __restrict__ W1,
                                                     const float* __restrict__ W2,
                                                     unsigned short* __restrict__ W1th,
                                                     unsigned short* __restrict__ W1tl,
                                                     unsigned short* __restrict__ W2th,
                                                     unsigned short* __restrict__ W2tl) {
    int b = blockIdx.x;
    const float* M = (b < 64) ? W1 : W2;
    unsigned short* H = (b < 64) ? W1th : W2th;
    unsigned short* L = (b < 64) ? W1tl : W2tl;
    int id = (b & 63) * 256 + threadIdx.x;
    float v = M[id];
    int k = id >> 7, c = id & 127;
    unsigned short h = f2bf(v);
    H[c * 128 + k] = h;
    L[c * 128 + k] = f2bf(v - bf2f(h));
}

// ---------------- CSR build: histogram -> scan -> fill ----------------
__global__ void hist_kernel(const int* __restrict__ dst, int* __restrict__ counts) {
    int e = blockIdx.x * blockDim.x + threadIdx.x;
    if (e < EE) atomicAdd(&counts[dst[e]], 1);
}

__global__ __launch_bounds__(SCAN_BLK) void scan_blocks(const int* __restrict__ counts,
                                                        int* __restrict__ rs,
                                                        int* __restrict__ bsum) {
    __shared__ int sd[SCAN_BLK];
    int tid = threadIdx.x;
    int gid = blockIdx.x * SCAN_BLK + tid;
    int v = (gid < NN) ? counts[gid] : 0;
    sd[tid] = v;
    __syncthreads();
    for (int o = 1; o < SCAN_BLK; o <<= 1) {
        int t = (tid >= o) ? sd[tid - o] : 0;
        __syncthreads();
        sd[tid] += t;
        __syncthreads();
    }
    if (gid < NN) rs[gid] = sd[tid] - v;
    if (tid == SCAN_BLK - 1) bsum[blockIdx.x] = sd[tid];
}

__global__ void scan_sums(int* __restrict__ bsum, int* __restrict__ rs) {
    if (threadIdx.x == 0 && blockIdx.x == 0) {
        int run = 0;
        for (int i = 0; i < NB_SCAN; ++i) { int t = bsum[i]; bsum[i] = run; run += t; }
        rs[NN] = EE;
    }
}

__global__ __launch_bounds__(SCAN_BLK) void scan_add(int* __restrict__ rs,
                                                     const int* __restrict__ bsum) {
    int gid = blockIdx.x * SCAN_BLK + threadIdx.x;
    if (gid < NN) rs[gid] += bsum[blockIdx.x];
}

// packed fill: one 8B store per edge {src, w_bits}
__global__ void fill_kernel(const int* __restrict__ src, const int* __restrict__ dst,
                            const float* __restrict__ w, const int* __restrict__ rs,
                            int* __restrict__ cursor, int2* __restrict__ csr) {
    int e = blockIdx.x * blockDim.x + threadIdx.x;
    if (e < EE) {
        int d = dst[e];
        int pos = atomicAdd(&cursor[d], 1);
        csr[rs[d] + pos] = make_int2(src[e], __float_as_int(w[e]));
    }
}

// ---------------- conv: f32 -> bf16 bits (for emb) ----------------
__global__ __launch_bounds__(256) void convx_kernel(const float* __restrict__ in,
                                                    unsigned short* __restrict__ outh,
                                                    int n4) {
    int i = blockIdx.x * 256 + threadIdx.x;
    if (i < n4) {
        float4 v = ((const float4*)in)[i];
        ushort4 h;
        h.x = f2bf(v.x); h.y = f2bf(v.y); h.z = f2bf(v.z); h.w = f2bf(v.w);
        ((ushort4*)outh)[i] = h;
    }
}

// ---------------- MFMA GEMM ----------------
// IN_F32: read X as f32 and convert inline; else X is bf16 bits.
// OUT_F32ACC: outf[o] = alpha*acc + outf[o]; else outh[o] = bf16(acc).
// block = 256 threads = 4 waves; block tile 64 rows x 128 cols; wave tile 32 x 64.
template <bool IN_F32, bool OUT_F32ACC>
__global__ __launch_bounds__(256) void gemm_mfma(const void* __restrict__ Xv,
                                                 const unsigned short* __restrict__ Mth,
                                                 const unsigned short* __restrict__ Mtl,
                                                 unsigned short* __restrict__ outh,
                                                 float* __restrict__ outf,
                                                 int nrows, float alpha) {
    const int wave = threadIdx.x >> 6;
    const int lane = threadIdx.x & 63;
    const int row0 = blockIdx.x * 64 + (wave >> 1) * 32;
    const int col0 = (wave & 1) * 64;
    const int lr = lane & 15;
    const int kg = lane >> 4;

    f32x4 acc[2][4];
    #pragma unroll
    for (int m = 0; m < 2; ++m)
        #pragma unroll
        for (int n = 0; n < 4; ++n)
            acc[m][n] = (f32x4){0.f, 0.f, 0.f, 0.f};

    #pragma unroll
    for (int k0 = 0; k0 < 128; k0 += 32) {
        s16x8 a[2];
        #pragma unroll
        for (int m = 0; m < 2; ++m) {
            int r = row0 + m * 16 + lr;
            if (r >= nrows) r = nrows - 1;
            if (IN_F32) {
                const float* xp = (const float*)Xv + (size_t)r * 128 + k0 + kg * 8;
                float4 f0 = ((const float4*)xp)[0];
                float4 f1 = ((const float4*)xp)[1];
                union { s16x8 v; unsigned short u[8]; } cv;
                cv.u[0] = f2bf(f0.x); cv.u[1] = f2bf(f0.y); cv.u[2] = f2bf(f0.z); cv.u[3] = f2bf(f0.w);
                cv.u[4] = f2bf(f1.x); cv.u[5] = f2bf(f1.y); cv.u[6] = f2bf(f1.z); cv.u[7] = f2bf(f1.w);
                a[m] = cv.v;
            } else {
                a[m] = *(const s16x8*)((const unsigned short*)Xv + (size_t)r * 128 + k0 + kg * 8);
            }
        }
        #pragma unroll
        for (int n = 0; n < 4; ++n) {
            const int c = col0 + n * 16 + lr;
            s16x8 bh = *(const s16x8*)(Mth + c * 128 + k0 + kg * 8);
            s16x8 bl = *(const s16x8*)(Mtl + c * 128 + k0 + kg * 8);
            #pragma unroll
            for (int m = 0; m < 2; ++m) {
                acc[m][n] = __builtin_amdgcn_mfma_f32_16x16x32_bf16(a[m], bh, acc[m][n], 0, 0, 0);
                acc[m][n] = __builtin_amdgcn_mfma_f32_16x16x32_bf16(a[m], bl, acc[m][n], 0, 0, 0);
            }
        }
    }

    // D layout: col = lane&15, row = (lane>>4)*4 + j   [m89]
    #pragma unroll
    for (int m = 0; m < 2; ++m) {
        #pragma unroll
        for (int n = 0; n < 4; ++n) {
            #pragma unroll
            for (int j = 0; j < 4; ++j) {
                int r = row0 + m * 16 + kg * 4 + j;
                int c = col0 + n * 16 + lr;
                if (r < nrows) {
                    size_t o = (size_t)r * 128 + c;
                    if (OUT_F32ACC) {
                        outf[o] = alpha * acc[m][n][j] + outf[o];
                    } else {
                        outh[o] = f2bf(acc[m][n][j]);
                    }
                }
            }
        }
    }
}

// ---------------- SpMM (CSR by dst, bf16 gather) ----------------
// MODE 0: plain, bf16 out.  MODE 1: +bias relu, bf16 out.  MODE 2: +bias, f32 out.
template <int MODE>
__global__ __launch_bounds__(256) void spmm_kernel(const unsigned short* __restrict__ h,
                                                   const int* __restrict__ rs,
                                                   const int2* __restrict__ csr,
                                                   const float* __restrict__ bias,
                                                   unsigned short* __restrict__ outh,
                                                   float* __restrict__ outf) {
    int node = blockIdx.x * 8 + (threadIdx.x >> 5);
    int lane = threadIdx.x & 31;
    if (node >= NN) return;
    int e = rs[node];
    const int re = rs[node + 1];
    float4 acc = make_float4(0.f, 0.f, 0.f, 0.f);
    for (; e + 1 < re; e += 2) {
        int2 p0 = csr[e];
        int2 p1 = csr[e + 1];
        float w0 = __int_as_float(p0.y);
        float w1 = __int_as_float(p1.y);
        ushort4 v0 = *(const ushort4*)(h + (size_t)p0.x * 128 + lane * 4);
        ushort4 v1 = *(const ushort4*)(h + (size_t)p1.x * 128 + lane * 4);
        acc.x += w0 * bf2f(v0.x); acc.y += w0 * bf2f(v0.y);
        acc.z += w0 * bf2f(v0.z); acc.w += w0 * bf2f(v0.w);
        acc.x += w1 * bf2f(v1.x); acc.y += w1 * bf2f(v1.y);
        acc.z += w1 * bf2f(v1.z); acc.w += w1 * bf2f(v1.w);
    }
    if (e < re) {
        int2 p0 = csr[e];
        float w0 = __int_as_float(p0.y);
        ushort4 v0 = *(const ushort4*)(h + (size_t)p0.x * 128 + lane * 4);
        acc.x += w0 * bf2f(v0.x); acc.y += w0 * bf2f(v0.y);
        acc.z += w0 * bf2f(v0.z); acc.w += w0 * bf2f(v0.w);
    }
    if (MODE != 0) {
        float4 b = ((const float4*)bias)[lane];
        acc.x += b.x; acc.y += b.y; acc.z += b.z; acc.w += b.w;
        if (MODE == 1) {
            acc.x = fmaxf(acc.x, 0.f); acc.y = fmaxf(acc.y, 0.f);
            acc.z = fmaxf(acc.z, 0.f); acc.w = fmaxf(acc.w, 0.f);
        }
    }
    if (MODE == 2) {
        ((float4*)(outf + (size_t)node * 128))[lane] = acc;
    } else {
        ushort4 o;
        o.x = f2bf(acc.x); o.y = f2bf(acc.y); o.z = f2bf(acc.z); o.w = f2bf(acc.w);
        ((ushort4*)(outh + (size_t)node * 128))[lane] = o;
    }
}

static inline size_t align_up(size_t x, size_t a) { return (x + a - 1) / a * a; }

extern "C" void kernel_launch(void* const* d_in, const int* in_sizes, int n_in,
                              void* d_out, int out_size, void* d_ws, size_t ws_size,
                              hipStream_t stream) {
    const float* x   = (const float*)d_in[0];
    const int*   esrc = (const int*)d_in[1];
    const int*   edst = (const int*)d_in[2];
    const float* ew  = (const float*)d_in[3];
    const float* W1  = (const float*)d_in[4];
    const float* b1  = (const float*)d_in[5];
    const float* W2  = (const float*)d_in[6];
    const float* b2  = (const float*)d_in[7];
    const float* Fm  = (const float*)d_in[8];
    const float* emb = (const float*)d_in[9];
    float* out = (float*)d_out;

    char* ws = (char*)d_ws;
    size_t off = 0;
    auto alloc = [&](size_t bytes) -> void* {
        void* p = ws + off;
        off = align_up(off + bytes, 256);
        return p;
    };
    unsigned short* B1 = (unsigned short*)alloc((size_t)NN * DD * 2);  // 12.8 MB
    unsigned short* B2 = (unsigned short*)alloc((size_t)NN * DD * 2);  // 12.8 MB
    float* Wmat   = (float*)alloc(128 * 128 * 4);
    int*   counts = (int*)alloc((size_t)NN * 4);
    int*   cursor = (int*)alloc((size_t)NN * 4);
    float* ssq    = (float*)alloc(256);
    int*   rs     = (int*)alloc((size_t)(NN + 1) * 4);
    int*   bsum   = (int*)alloc(64 * 4);
    int2*  csr    = (int2*)alloc((size_t)EE * 8);                      // 4.8 MB packed
    unsigned short* W1th = (unsigned short*)alloc(128 * 128 * 2);
    unsigned short* W1tl = (unsigned short*)alloc(128 * 128 * 2);
    unsigned short* W2th = (unsigned short*)alloc(128 * 128 * 2);
    unsigned short* W2tl = (unsigned short*)alloc(128 * 128 * 2);
    unsigned short* Wmth = (unsigned short*)alloc(128 * 128 * 2);
    unsigned short* Wmtl = (unsigned short*)alloc(128 * 128 * 2);
    if (off > ws_size) return;  // workspace too small -> fail visibly

    // zero [counts | cursor | ssq]
    size_t zero_bytes = (size_t)((char*)ssq - (char*)counts) + 256;
    hipMemsetAsync(counts, 0, zero_bytes, stream);

    // projection matrix + weight conversions
    wmat_kernel<<<128, 128, 0, stream>>>(Fm, Wmat, ssq);
    wsplit_kernel<<<64, 256, 0, stream>>>(Wmat, ssq, Wmth, Wmtl);
    convm2_kernel<<<128, 256, 0, stream>>>(W1, W2, W1th, W1tl, W2th, W2tl);

    // CSR build (by dst)
    hist_kernel<<<(EE + 255) / 256, 256, 0, stream>>>(edst, counts);
    scan_blocks<<<NB_SCAN, SCAN_BLK, 0, stream>>>(counts, rs, bsum);
    scan_sums<<<1, 64, 0, stream>>>(bsum, rs);
    scan_add<<<NB_SCAN, SCAN_BLK, 0, stream>>>(rs, bsum);
    fill_kernel<<<(EE + 255) / 256, 256, 0, stream>>>(esrc, edst, ew, rs, cursor, csr);

    const int n4 = NN * DD / 4;
    const int conv_grid = (n4 + 255) / 256;     // 6250
    const int gemm_grid = (NN + 63) / 64;       // 782
    const int spmm_grid = (NN + 7) / 8;         // 6250

    // h1 = bf16(x @ W1) -> B1
    gemm_mfma<true, false><<<gemm_grid, 256, 0, stream>>>(x, W1th, W1tl, B1, nullptr, NN, 1.0f);
    // h = bf16(relu(spmm(h1) + b1)) -> B2
    spmm_kernel<1><<<spmm_grid, 256, 0, stream>>>(B1, rs, csr, b1, B2, nullptr);
    // h2 = bf16(h @ W2) -> B1
    gemm_mfma<false, false><<<gemm_grid, 256, 0, stream>>>(B2, W2th, W2tl, B1, nullptr, NN, 1.0f);
    // base = spmm(h2) + b2 -> out (f32)
    spmm_kernel<2><<<spmm_grid, 256, 0, stream>>>(B1, rs, csr, b2, nullptr, out);
    // emb -> bf16 -> B2 (B2 free after gemm2)
    convx_kernel<<<conv_grid, 256, 0, stream>>>(emb, B2, n4);
    // s3 = bf16(spmm(emb)) -> B1 (B1 free after spmm2)
    spmm_kernel<0><<<spmm_grid, 256, 0, stream>>>(B2, rs, csr, nullptr, B1, nullptr);
    // out = KAPPA * (s3 @ Wmat) + out
    gemm_mfma<false, true><<<gemm_grid, 256, 0, stream>>>(B1, Wmth, Wmtl, nullptr, out, NN, KAPPA_C);
}

// Round 4
// 241.182 us; speedup vs baseline: 2.2952x; 1.1425x over previous
//
#include <hip/hip_runtime.h>
#include <math.h>

#define NN 50000
#define EE 600000
#define DD 128
#define KAPPA_C 0.95f
#define EPS_C 1e-5f
#define SCAN_BLK 1024
#define NB_SCAN ((NN + SCAN_BLK - 1) / SCAN_BLK)   // 49
#define NSLICE 8
#define SLICE_N ((NN + NSLICE - 1) / NSLICE)       // 6250
#define FCHUNK 192                                  // chunks per slice

typedef short s16x8 __attribute__((ext_vector_type(8)));   // 8 bf16 (4 VGPRs)
typedef float f32x4 __attribute__((ext_vector_type(4)));

// float -> bf16 bits, round-to-nearest-even
__device__ __forceinline__ unsigned short f2bf(float f) {
    union { float f; unsigned int u; } v;
    v.f = f;
    unsigned int r = v.u + 0x7fffu + ((v.u >> 16) & 1u);
    return (unsigned short)(r >> 16);
}
__device__ __forceinline__ float bf2f(unsigned short b) {
    union { unsigned int u; float f; } v;
    v.u = ((unsigned int)b) << 16;
    return v.f;
}

// ---------------- W = Fm^T Fm, plus sum of squares ----------------
__global__ __launch_bounds__(128) void wmat_kernel(const float* __restrict__ Fm,
                                                   float* __restrict__ W,
                                                   float* __restrict__ ssq) {
    const int i = blockIdx.x;
    const int j = threadIdx.x;
    float acc = 0.f;
    #pragma unroll 8
    for (int k = 0; k < 128; ++k)
        acc += Fm[k * 128 + i] * Fm[k * 128 + j];
    W[i * 128 + j] = acc;
    __shared__ float red[128];
    red[j] = acc * acc;
    __syncthreads();
    for (int o = 64; o > 0; o >>= 1) {
        if (j < o) red[j] += red[j + o];
        __syncthreads();
    }
    if (j == 0) atomicAdd(ssq, red[0]);
}

// fused: scale Wmat by 1/(norm+eps) if norm>1, emit transposed split-bf16
__global__ __launch_bounds__(256) void wsplit_kernel(const float* __restrict__ Wmat,
                                                     const float* __restrict__ ssq,
                                                     unsigned short* __restrict__ Mth,
                                                     unsigned short* __restrict__ Mtl) {
    int id = blockIdx.x * 256 + threadIdx.x;
    float n = sqrtf(*ssq);
    float s = (n > 1.0f) ? 1.0f / (n + EPS_C) : 1.0f;
    float v = Wmat[id] * s;
    int k = id >> 7, c = id & 127;
    unsigned short h = f2bf(v);
    Mth[c * 128 + k] = h;
    Mtl[c * 128 + k] = f2bf(v - bf2f(h));
}

// W1 and W2 -> transposed split bf16, one dispatch
__global__ __launch_bounds__(256) void convm2_kernel(const float* __restrict__ W1,
                                                     const float* __restrict__ W2,
                                                     unsigned short* __restrict__ W1th,
                                                     unsigned short* __restrict__ W1tl,
                                                     unsigned short* __restrict__ W2th,
                                                     unsigned short* __restrict__ W2tl) {
    int b = blockIdx.x;
    const float* M = (b < 64) ? W1 : W2;
    unsigned short* H = (b < 64) ? W1th : W2th;
    unsigned short* L = (b < 64) ? W1tl : W2tl;
    int id = (b & 63) * 256 + threadIdx.x;
    float v = M[id];
    int k = id >> 7, c = id & 127;
    unsigned short h = f2bf(v);
    H[c * 128 + k] = h;
    L[c * 128 + k] = f2bf(v - bf2f(h));
}

// ---------------- CSR build (XCD-sliced: slice = blockIdx & 7) ----------------
__global__ __launch_bounds__(256) void hist_kernel(const int* __restrict__ dst,
                                                   int* __restrict__ counts) {
    const int slice = blockIdx.x & (NSLICE - 1);
    const int lo = slice * SLICE_N;
    const int hi = lo + SLICE_N;           // NN is a multiple of SLICE_N*8? 6250*8=50000 exact
    const int chunk = blockIdx.x >> 3;
    const int per = (EE + FCHUNK - 1) / FCHUNK;   // 3125
    const int e0 = chunk * per;
    int e1 = e0 + per; if (e1 > EE) e1 = EE;
    for (int e = e0 + threadIdx.x; e < e1; e += 256) {
        int d = dst[e];
        if (d >= lo && d < hi) atomicAdd(&counts[d], 1);
    }
}

__global__ __launch_bounds__(SCAN_BLK) void scan_blocks(const int* __restrict__ counts,
                                                        int* __restrict__ rs,
                                                        int* __restrict__ bsum) {
    __shared__ int sd[SCAN_BLK];
    int tid = threadIdx.x;
    int gid = blockIdx.x * SCAN_BLK + tid;
    int v = (gid < NN) ? counts[gid] : 0;
    sd[tid] = v;
    __syncthreads();
    for (int o = 1; o < SCAN_BLK; o <<= 1) {
        int t = (tid >= o) ? sd[tid - o] : 0;
        __syncthreads();
        sd[tid] += t;
        __syncthreads();
    }
    if (gid < NN) rs[gid] = sd[tid] - v;
    if (tid == SCAN_BLK - 1) bsum[blockIdx.x] = sd[tid];
}

// fused block-offset add (each block prefix-sums bsum itself; kills scan_sums dispatch)
__global__ __launch_bounds__(SCAN_BLK) void scan_add(int* __restrict__ rs,
                                                     const int* __restrict__ bsum) {
    __shared__ int pre;
    if (threadIdx.x == 0) {
        int run = 0;
        for (int i = 0; i < (int)blockIdx.x; ++i) run += bsum[i];
        pre = run;
    }
    __syncthreads();
    int gid = blockIdx.x * SCAN_BLK + threadIdx.x;
    if (gid < NN) rs[gid] += pre;
    if (gid == NN - 1) rs[NN] = EE;
}

// XCD-sliced packed fill: one 8B store per edge, write-locality per slice
__global__ __launch_bounds__(256) void fill_kernel(const int* __restrict__ src,
                                                   const int* __restrict__ dst,
                                                   const float* __restrict__ w,
                                                   const int* __restrict__ rs,
                                                   int* __restrict__ cursor,
                                                   int2* __restrict__ csr) {
    const int slice = blockIdx.x & (NSLICE - 1);
    const int lo = slice * SLICE_N;
    const int hi = lo + SLICE_N;
    const int chunk = blockIdx.x >> 3;
    const int per = (EE + FCHUNK - 1) / FCHUNK;
    const int e0 = chunk * per;
    int e1 = e0 + per; if (e1 > EE) e1 = EE;
    for (int e = e0 + threadIdx.x; e < e1; e += 256) {
        int d = dst[e];
        if (d >= lo && d < hi) {
            int pos = atomicAdd(&cursor[d], 1);
            csr[rs[d] + pos] = make_int2(src[e], __float_as_int(w[e]));
        }
    }
}

// ---------------- MFMA GEMM: outh[r*ostride + ocol + c] = bf16(X @ (Mth+Mtl)) ----------------
// block = 256 threads = 4 waves; block tile 64 rows x 128 cols; wave tile 32 x 64.
template <bool IN_F32>
__global__ __launch_bounds__(256) void gemm_mfma(const void* __restrict__ Xv,
                                                 const unsigned short* __restrict__ Mth,
                                                 const unsigned short* __restrict__ Mtl,
                                                 unsigned short* __restrict__ outh,
                                                 int ostride, int ocol, int nrows) {
    const int wave = threadIdx.x >> 6;
    const int lane = threadIdx.x & 63;
    const int row0 = blockIdx.x * 64 + (wave >> 1) * 32;
    const int col0 = (wave & 1) * 64;
    const int lr = lane & 15;
    const int kg = lane >> 4;

    f32x4 acc[2][4];
    #pragma unroll
    for (int m = 0; m < 2; ++m)
        #pragma unroll
        for (int n = 0; n < 4; ++n)
            acc[m][n] = (f32x4){0.f, 0.f, 0.f, 0.f};

    #pragma unroll
    for (int k0 = 0; k0 < 128; k0 += 32) {
        s16x8 a[2];
        #pragma unroll
        for (int m = 0; m < 2; ++m) {
            int r = row0 + m * 16 + lr;
            if (r >= nrows) r = nrows - 1;
            if (IN_F32) {
                const float* xp = (const float*)Xv + (size_t)r * 128 + k0 + kg * 8;
                float4 f0 = ((const float4*)xp)[0];
                float4 f1 = ((const float4*)xp)[1];
                union { s16x8 v; unsigned short u[8]; } cv;
                cv.u[0] = f2bf(f0.x); cv.u[1] = f2bf(f0.y); cv.u[2] = f2bf(f0.z); cv.u[3] = f2bf(f0.w);
                cv.u[4] = f2bf(f1.x); cv.u[5] = f2bf(f1.y); cv.u[6] = f2bf(f1.z); cv.u[7] = f2bf(f1.w);
                a[m] = cv.v;
            } else {
                a[m] = *(const s16x8*)((const unsigned short*)Xv + (size_t)r * 128 + k0 + kg * 8);
            }
        }
        #pragma unroll
        for (int n = 0; n < 4; ++n) {
            const int c = col0 + n * 16 + lr;
            s16x8 bh = *(const s16x8*)(Mth + c * 128 + k0 + kg * 8);
            s16x8 bl = *(const s16x8*)(Mtl + c * 128 + k0 + kg * 8);
            #pragma unroll
            for (int m = 0; m < 2; ++m) {
                acc[m][n] = __builtin_amdgcn_mfma_f32_16x16x32_bf16(a[m], bh, acc[m][n], 0, 0, 0);
                acc[m][n] = __builtin_amdgcn_mfma_f32_16x16x32_bf16(a[m], bl, acc[m][n], 0, 0, 0);
            }
        }
    }

    // D layout: col = lane&15, row = (lane>>4)*4 + j   [m89]
    #pragma unroll
    for (int m = 0; m < 2; ++m) {
        #pragma unroll
        for (int n = 0; n < 4; ++n) {
            #pragma unroll
            for (int j = 0; j < 4; ++j) {
                int r = row0 + m * 16 + kg * 4 + j;
                int c = col0 + n * 16 + lr;
                if (r < nrows)
                    outh[(size_t)r * ostride + ocol + c] = f2bf(acc[m][n][j]);
            }
        }
    }
}

// ---------------- SpMM 1: h = bf16(relu(A @ h1 + b1)), 2 nodes/wave ----------------
__global__ __launch_bounds__(256) void spmm_relu(const unsigned short* __restrict__ h,
                                                 const int* __restrict__ rs,
                                                 const int2* __restrict__ csr,
                                                 const float* __restrict__ bias,
                                                 unsigned short* __restrict__ outh) {
    int node = blockIdx.x * 8 + (threadIdx.x >> 5);
    int lane = threadIdx.x & 31;
    if (node >= NN) return;
    int e = rs[node];
    const int re = rs[node + 1];
    float4 acc = make_float4(0.f, 0.f, 0.f, 0.f);
    for (; e + 1 < re; e += 2) {
        int2 p0 = csr[e];
        int2 p1 = csr[e + 1];
        float w0 = __int_as_float(p0.y);
        float w1 = __int_as_float(p1.y);
        ushort4 v0 = *(const ushort4*)(h + (size_t)p0.x * 128 + lane * 4);
        ushort4 v1 = *(const ushort4*)(h + (size_t)p1.x * 128 + lane * 4);
        acc.x += w0 * bf2f(v0.x); acc.y += w0 * bf2f(v0.y);
        acc.z += w0 * bf2f(v0.z); acc.w += w0 * bf2f(v0.w);
        acc.x += w1 * bf2f(v1.x); acc.y += w1 * bf2f(v1.y);
        acc.z += w1 * bf2f(v1.z); acc.w += w1 * bf2f(v1.w);
    }
    if (e < re) {
        int2 p0 = csr[e];
        float w0 = __int_as_float(p0.y);
        ushort4 v0 = *(const ushort4*)(h + (size_t)p0.x * 128 + lane * 4);
        acc.x += w0 * bf2f(v0.x); acc.y += w0 * bf2f(v0.y);
        acc.z += w0 * bf2f(v0.z); acc.w += w0 * bf2f(v0.w);
    }
    float4 b = ((const float4*)bias)[lane];
    acc.x = fmaxf(acc.x + b.x, 0.f); acc.y = fmaxf(acc.y + b.y, 0.f);
    acc.z = fmaxf(acc.z + b.z, 0.f); acc.w = fmaxf(acc.w + b.w, 0.f);
    ushort4 o;
    o.x = f2bf(acc.x); o.y = f2bf(acc.y); o.z = f2bf(acc.z); o.w = f2bf(acc.w);
    ((ushort4*)(outh + (size_t)node * 128))[lane] = o;
}

// ---------------- fused final SpMM: out = A@h2 + KAPPA*(A@E) + b2 ----------------
// big: [NN][256] bf16, cols 0..127 = h2, 128..255 = E. One node per 64-lane wave;
// lane gathers 8B of the 512B row; halves combined via shfl(lane+32).
__global__ __launch_bounds__(256) void spmm_fused(const unsigned short* __restrict__ big,
                                                  const int* __restrict__ rs,
                                                  const int2* __restrict__ csr,
                                                  const float* __restrict__ b2,
                                                  float* __restrict__ out) {
    int node = blockIdx.x * 4 + (threadIdx.x >> 6);
    int lane = threadIdx.x & 63;
    if (node >= NN) return;
    int e = rs[node];
    const int re = rs[node + 1];
    float4 acc = make_float4(0.f, 0.f, 0.f, 0.f);
    for (; e + 1 < re; e += 2) {
        int2 p0 = csr[e];
        int2 p1 = csr[e + 1];
        float w0 = __int_as_float(p0.y);
        float w1 = __int_as_float(p1.y);
        ushort4 v0 = *(const ushort4*)(big + (size_t)p0.x * 256 + lane * 4);
        ushort4 v1 = *(const ushort4*)(big + (size_t)p1.x * 256 + lane * 4);
        acc.x += w0 * bf2f(v0.x); acc.y += w0 * bf2f(v0.y);
        acc.z += w0 * bf2f(v0.z); acc.w += w0 * bf2f(v0.w);
        acc.x += w1 * bf2f(v1.x); acc.y += w1 * bf2f(v1.y);
        acc.z += w1 * bf2f(v1.z); acc.w += w1 * bf2f(v1.w);
    }
    if (e < re) {
        int2 p0 = csr[e];
        float w0 = __int_as_float(p0.y);
        ushort4 v0 = *(const ushort4*)(big + (size_t)p0.x * 256 + lane * 4);
        acc.x += w0 * bf2f(v0.x); acc.y += w0 * bf2f(v0.y);
        acc.z += w0 * bf2f(v0.z); acc.w += w0 * bf2f(v0.w);
    }
    // lanes 0..31 hold h2-channels; lanes 32..63 hold E-channels of the same node
    int peer = (lane & 31) + 32;
    float ex = __shfl(acc.x, peer);
    float ey = __shfl(acc.y, peer);
    float ez = __shfl(acc.z, peer);
    float ew4 = __shfl(acc.w, peer);
    if (lane < 32) {
        float4 b = ((const float4*)b2)[lane];
        float4 r;
        r.x = acc.x + KAPPA_C * ex + b.x;
        r.y = acc.y + KAPPA_C * ey + b.y;
        r.z = acc.z + KAPPA_C * ez + b.z;
        r.w = acc.w + KAPPA_C * ew4 + b.w;
        ((float4*)(out + (size_t)node * 128))[lane] = r;
    }
}

static inline size_t align_up(size_t x, size_t a) { return (x + a - 1) / a * a; }

extern "C" void kernel_launch(void* const* d_in, const int* in_sizes, int n_in,
                              void* d_out, int out_size, void* d_ws, size_t ws_size,
                              hipStream_t stream) {
    const float* x   = (const float*)d_in[0];
    const int*   esrc = (const int*)d_in[1];
    const int*   edst = (const int*)d_in[2];
    const float* ew  = (const float*)d_in[3];
    const float* W1  = (const float*)d_in[4];
    const float* b1  = (const float*)d_in[5];
    const float* W2  = (const float*)d_in[6];
    const float* b2  = (const float*)d_in[7];
    const float* Fm  = (const float*)d_in[8];
    const float* emb = (const float*)d_in[9];
    float* out = (float*)d_out;

    char* ws = (char*)d_ws;
    size_t off = 0;
    auto alloc = [&](size_t bytes) -> void* {
        void* p = ws + off;
        off = align_up(off + bytes, 256);
        return p;
    };
    unsigned short* B1  = (unsigned short*)alloc((size_t)NN * DD * 2);      // 12.8 MB (h1, then h2 staging not needed)
    unsigned short* BIG = (unsigned short*)alloc((size_t)NN * 256 * 2);     // 25.6 MB interleaved [h2 | E]
    float* Wmat   = (float*)alloc(128 * 128 * 4);
    int*   counts = (int*)alloc((size_t)NN * 4);
    int*   cursor = (int*)alloc((size_t)NN * 4);
    float* ssq    = (float*)alloc(256);
    int*   rs     = (int*)alloc((size_t)(NN + 1) * 4);
    int*   bsum   = (int*)alloc(64 * 4);
    int2*  csr    = (int2*)alloc((size_t)EE * 8);                           // 4.8 MB
    unsigned short* W1th = (unsigned short*)alloc(128 * 128 * 2);
    unsigned short* W1tl = (unsigned short*)alloc(128 * 128 * 2);
    unsigned short* W2th = (unsigned short*)alloc(128 * 128 * 2);
    unsigned short* W2tl = (unsigned short*)alloc(128 * 128 * 2);
    unsigned short* Wmth = (unsigned short*)alloc(128 * 128 * 2);
    unsigned short* Wmtl = (unsigned short*)alloc(128 * 128 * 2);
    if (off > ws_size) return;  // workspace too small -> fail visibly

    // h scratch lives in d_out (bf16, first 12.8 MB); dead before spmm_fused overwrites out
    unsigned short* H = (unsigned short*)d_out;

    // zero [counts | cursor | ssq]
    size_t zero_bytes = (size_t)((char*)ssq - (char*)counts) + 256;
    hipMemsetAsync(counts, 0, zero_bytes, stream);

    // projection matrix + weight conversions
    wmat_kernel<<<128, 128, 0, stream>>>(Fm, Wmat, ssq);
    wsplit_kernel<<<64, 256, 0, stream>>>(Wmat, ssq, Wmth, Wmtl);
    convm2_kernel<<<128, 256, 0, stream>>>(W1, W2, W1th, W1tl, W2th, W2tl);

    // CSR build (XCD-sliced)
    const int sgrid = NSLICE * FCHUNK;   // 1536
    hist_kernel<<<sgrid, 256, 0, stream>>>(edst, counts);
    scan_blocks<<<NB_SCAN, SCAN_BLK, 0, stream>>>(counts, rs, bsum);
    scan_add<<<NB_SCAN, SCAN_BLK, 0, stream>>>(rs, bsum);
    fill_kernel<<<sgrid, 256, 0, stream>>>(esrc, edst, ew, rs, cursor, csr);

    const int gemm_grid = (NN + 63) / 64;     // 782
    const int spmm_grid1 = (NN + 7) / 8;      // 6250
    const int spmm_gridF = (NN + 3) / 4;      // 12500

    // h1 = bf16(x @ W1) -> B1
    gemm_mfma<true><<<gemm_grid, 256, 0, stream>>>(x, W1th, W1tl, B1, 128, 0, NN);
    // E = bf16(emb @ Wm) -> BIG[:,128:256]   (kappa*(A emb)W == kappa*A(emb W))
    gemm_mfma<true><<<gemm_grid, 256, 0, stream>>>(emb, Wmth, Wmtl, BIG, 256, 128, NN);
    // h = bf16(relu(A @ h1 + b1)) -> H (in d_out bytes)
    spmm_relu<<<spmm_grid1, 256, 0, stream>>>(B1, rs, csr, b1, H);
    // h2 = bf16(h @ W2) -> BIG[:,0:128]
    gemm_mfma<false><<<gemm_grid, 256, 0, stream>>>(H, W2th, W2tl, BIG, 256, 0, NN);
    // out = A@h2 + KAPPA*(A@E) + b2  (single fused gather pass)
    spmm_fused<<<spmm_gridF, 256, 0, stream>>>(BIG, rs, csr, b2, out);
}

// Round 5
// 233.198 us; speedup vs baseline: 2.3737x; 1.0342x over previous
//
#include <hip/hip_runtime.h>
#include <math.h>

#define NN 50000
#define EE 600000
#define DD 128
#define KAPPA_C 0.95f
#define EPS_C 1e-5f
#define SCAN_BLK 1024
#define NB_SCAN ((NN + SCAN_BLK - 1) / SCAN_BLK)   // 49
#define NSLICE 8
#define SLICE_N ((NN + NSLICE - 1) / NSLICE)       // 6250
#define FCHUNK 192                                  // chunks per slice

typedef short s16x8 __attribute__((ext_vector_type(8)));   // 8 bf16 (4 VGPRs)
typedef float f32x4 __attribute__((ext_vector_type(4)));

// float -> bf16 bits, round-to-nearest-even
__device__ __forceinline__ unsigned short f2bf(float f) {
    union { float f; unsigned int u; } v;
    v.f = f;
    unsigned int r = v.u + 0x7fffu + ((v.u >> 16) & 1u);
    return (unsigned short)(r >> 16);
}
__device__ __forceinline__ float bf2f(unsigned short b) {
    union { unsigned int u; float f; } v;
    v.u = ((unsigned int)b) << 16;
    return v.f;
}

// ---------------- W = Fm^T Fm, plus sum of squares ----------------
__global__ __launch_bounds__(128) void wmat_kernel(const float* __restrict__ Fm,
                                                   float* __restrict__ W,
                                                   float* __restrict__ ssq) {
    const int i = blockIdx.x;
    const int j = threadIdx.x;
    float acc = 0.f;
    #pragma unroll 8
    for (int k = 0; k < 128; ++k)
        acc += Fm[k * 128 + i] * Fm[k * 128 + j];
    W[i * 128 + j] = acc;
    __shared__ float red[128];
    red[j] = acc * acc;
    __syncthreads();
    for (int o = 64; o > 0; o >>= 1) {
        if (j < o) red[j] += red[j + o];
        __syncthreads();
    }
    if (j == 0) atomicAdd(ssq, red[0]);
}

// fused: scale Wmat by 1/(norm+eps) if norm>1, emit transposed split-bf16
__global__ __launch_bounds__(256) void wsplit_kernel(const float* __restrict__ Wmat,
                                                     const float* __restrict__ ssq,
                                                     unsigned short* __restrict__ Mth,
                                                     unsigned short* __restrict__ Mtl) {
    int id = blockIdx.x * 256 + threadIdx.x;
    float n = sqrtf(*ssq);
    float s = (n > 1.0f) ? 1.0f / (n + EPS_C) : 1.0f;
    float v = Wmat[id] * s;
    int k = id >> 7, c = id & 127;
    unsigned short h = f2bf(v);
    Mth[c * 128 + k] = h;
    Mtl[c * 128 + k] = f2bf(v - bf2f(h));
}

// W1 and W2 -> transposed split bf16, one dispatch
__global__ __launch_bounds__(256) void convm2_kernel(const float* __restrict__ W1,
                                                     const float* __restrict__ W2,
                                                     unsigned short* __restrict__ W1th,
                                                     unsigned short* __restrict__ W1tl,
                                                     unsigned short* __restrict__ W2th,
                                                     unsigned short* __restrict__ W2tl) {
    int b = blockIdx.x;
    const float* M = (b < 64) ? W1 : W2;
    unsigned short* H = (b < 64) ? W1th : W2th;
    unsigned short* L = (b < 64) ? W1tl : W2tl;
    int id = (b & 63) * 256 + threadIdx.x;
    float v = M[id];
    int k = id >> 7, c = id & 127;
    unsigned short h = f2bf(v);
    H[c * 128 + k] = h;
    L[c * 128 + k] = f2bf(v - bf2f(h));
}

// ---------------- CSR build (XCD-sliced: slice = blockIdx & 7) ----------------
__global__ __launch_bounds__(256) void hist_kernel(const int* __restrict__ dst,
                                                   int* __restrict__ counts) {
    const int slice = blockIdx.x & (NSLICE - 1);
    const int lo = slice * SLICE_N;
    const int hi = lo + SLICE_N;
    const int chunk = blockIdx.x >> 3;
    const int per = (EE + FCHUNK - 1) / FCHUNK;   // 3125
    const int e0 = chunk * per;
    int e1 = e0 + per; if (e1 > EE) e1 = EE;
    for (int e = e0 + threadIdx.x; e < e1; e += 256) {
        int d = dst[e];
        if (d >= lo && d < hi) atomicAdd(&counts[d], 1);
    }
}

__global__ __launch_bounds__(SCAN_BLK) void scan_blocks(const int* __restrict__ counts,
                                                        int* __restrict__ rs,
                                                        int* __restrict__ bsum) {
    __shared__ int sd[SCAN_BLK];
    int tid = threadIdx.x;
    int gid = blockIdx.x * SCAN_BLK + tid;
    int v = (gid < NN) ? counts[gid] : 0;
    sd[tid] = v;
    __syncthreads();
    for (int o = 1; o < SCAN_BLK; o <<= 1) {
        int t = (tid >= o) ? sd[tid - o] : 0;
        __syncthreads();
        sd[tid] += t;
        __syncthreads();
    }
    if (gid < NN) rs[gid] = sd[tid] - v;
    if (tid == SCAN_BLK - 1) bsum[blockIdx.x] = sd[tid];
}

// fused block-offset add
__global__ __launch_bounds__(SCAN_BLK) void scan_add(int* __restrict__ rs,
                                                     const int* __restrict__ bsum) {
    __shared__ int pre;
    if (threadIdx.x == 0) {
        int run = 0;
        for (int i = 0; i < (int)blockIdx.x; ++i) run += bsum[i];
        pre = run;
    }
    __syncthreads();
    int gid = blockIdx.x * SCAN_BLK + threadIdx.x;
    if (gid < NN) rs[gid] += pre;
    if (gid == NN - 1) rs[NN] = EE;
}

// XCD-sliced packed fill
__global__ __launch_bounds__(256) void fill_kernel(const int* __restrict__ src,
                                                   const int* __restrict__ dst,
                                                   const float* __restrict__ w,
                                                   const int* __restrict__ rs,
                                                   int* __restrict__ cursor,
                                                   int2* __restrict__ csr) {
    const int slice = blockIdx.x & (NSLICE - 1);
    const int lo = slice * SLICE_N;
    const int hi = lo + SLICE_N;
    const int chunk = blockIdx.x >> 3;
    const int per = (EE + FCHUNK - 1) / FCHUNK;
    const int e0 = chunk * per;
    int e1 = e0 + per; if (e1 > EE) e1 = EE;
    for (int e = e0 + threadIdx.x; e < e1; e += 256) {
        int d = dst[e];
        if (d >= lo && d < hi) {
            int pos = atomicAdd(&cursor[d], 1);
            csr[rs[d] + pos] = make_int2(src[e], __float_as_int(w[e]));
        }
    }
}

// ---------------- MFMA GEMM: outh[r*ostride + ocol + c] = bf16(X @ (Mth+Mtl)) ----------------
template <bool IN_F32>
__global__ __launch_bounds__(256) void gemm_mfma(const void* __restrict__ Xv,
                                                 const unsigned short* __restrict__ Mth,
                                                 const unsigned short* __restrict__ Mtl,
                                                 unsigned short* __restrict__ outh,
                                                 int ostride, int ocol, int nrows) {
    const int wave = threadIdx.x >> 6;
    const int lane = threadIdx.x & 63;
    const int row0 = blockIdx.x * 64 + (wave >> 1) * 32;
    const int col0 = (wave & 1) * 64;
    const int lr = lane & 15;
    const int kg = lane >> 4;

    f32x4 acc[2][4];
    #pragma unroll
    for (int m = 0; m < 2; ++m)
        #pragma unroll
        for (int n = 0; n < 4; ++n)
            acc[m][n] = (f32x4){0.f, 0.f, 0.f, 0.f};

    #pragma unroll
    for (int k0 = 0; k0 < 128; k0 += 32) {
        s16x8 a[2];
        #pragma unroll
        for (int m = 0; m < 2; ++m) {
            int r = row0 + m * 16 + lr;
            if (r >= nrows) r = nrows - 1;
            if (IN_F32) {
                const float* xp = (const float*)Xv + (size_t)r * 128 + k0 + kg * 8;
                float4 f0 = ((const float4*)xp)[0];
                float4 f1 = ((const float4*)xp)[1];
                union { s16x8 v; unsigned short u[8]; } cv;
                cv.u[0] = f2bf(f0.x); cv.u[1] = f2bf(f0.y); cv.u[2] = f2bf(f0.z); cv.u[3] = f2bf(f0.w);
                cv.u[4] = f2bf(f1.x); cv.u[5] = f2bf(f1.y); cv.u[6] = f2bf(f1.z); cv.u[7] = f2bf(f1.w);
                a[m] = cv.v;
            } else {
                a[m] = *(const s16x8*)((const unsigned short*)Xv + (size_t)r * 128 + k0 + kg * 8);
            }
        }
        #pragma unroll
        for (int n = 0; n < 4; ++n) {
            const int c = col0 + n * 16 + lr;
            s16x8 bh = *(const s16x8*)(Mth + c * 128 + k0 + kg * 8);
            s16x8 bl = *(const s16x8*)(Mtl + c * 128 + k0 + kg * 8);
            #pragma unroll
            for (int m = 0; m < 2; ++m) {
                acc[m][n] = __builtin_amdgcn_mfma_f32_16x16x32_bf16(a[m], bh, acc[m][n], 0, 0, 0);
                acc[m][n] = __builtin_amdgcn_mfma_f32_16x16x32_bf16(a[m], bl, acc[m][n], 0, 0, 0);
            }
        }
    }

    // D layout: col = lane&15, row = (lane>>4)*4 + j   [m89]
    #pragma unroll
    for (int m = 0; m < 2; ++m) {
        #pragma unroll
        for (int n = 0; n < 4; ++n) {
            #pragma unroll
            for (int j = 0; j < 4; ++j) {
                int r = row0 + m * 16 + kg * 4 + j;
                int c = col0 + n * 16 + lr;
                if (r < nrows)
                    outh[(size_t)r * ostride + ocol + c] = f2bf(acc[m][n][j]);
            }
        }
    }
}

// ---------------- SpMM 1: h = bf16(relu(A @ h1 + b1)), 32 lanes/node, 4-edge unroll ----------------
__global__ __launch_bounds__(256) void spmm_relu(const unsigned short* __restrict__ h,
                                                 const int* __restrict__ rs,
                                                 const int2* __restrict__ csr,
                                                 const float* __restrict__ bias,
                                                 unsigned short* __restrict__ outh) {
    int node = blockIdx.x * 8 + (threadIdx.x >> 5);
    int lane = threadIdx.x & 31;
    if (node >= NN) return;
    int e = rs[node];
    const int re = rs[node + 1];
    float4 acc = make_float4(0.f, 0.f, 0.f, 0.f);
    for (; e + 3 < re; e += 4) {
        int2 p0 = csr[e];
        int2 p1 = csr[e + 1];
        int2 p2 = csr[e + 2];
        int2 p3 = csr[e + 3];
        ushort4 v0 = *(const ushort4*)(h + (size_t)p0.x * 128 + lane * 4);
        ushort4 v1 = *(const ushort4*)(h + (size_t)p1.x * 128 + lane * 4);
        ushort4 v2 = *(const ushort4*)(h + (size_t)p2.x * 128 + lane * 4);
        ushort4 v3 = *(const ushort4*)(h + (size_t)p3.x * 128 + lane * 4);
        float w0 = __int_as_float(p0.y), w1 = __int_as_float(p1.y);
        float w2 = __int_as_float(p2.y), w3 = __int_as_float(p3.y);
        acc.x += w0 * bf2f(v0.x) + w1 * bf2f(v1.x) + w2 * bf2f(v2.x) + w3 * bf2f(v3.x);
        acc.y += w0 * bf2f(v0.y) + w1 * bf2f(v1.y) + w2 * bf2f(v2.y) + w3 * bf2f(v3.y);
        acc.z += w0 * bf2f(v0.z) + w1 * bf2f(v1.z) + w2 * bf2f(v2.z) + w3 * bf2f(v3.z);
        acc.w += w0 * bf2f(v0.w) + w1 * bf2f(v1.w) + w2 * bf2f(v2.w) + w3 * bf2f(v3.w);
    }
    for (; e < re; ++e) {
        int2 p0 = csr[e];
        float w0 = __int_as_float(p0.y);
        ushort4 v0 = *(const ushort4*)(h + (size_t)p0.x * 128 + lane * 4);
        acc.x += w0 * bf2f(v0.x); acc.y += w0 * bf2f(v0.y);
        acc.z += w0 * bf2f(v0.z); acc.w += w0 * bf2f(v0.w);
    }
    float4 b = ((const float4*)bias)[lane];
    acc.x = fmaxf(acc.x + b.x, 0.f); acc.y = fmaxf(acc.y + b.y, 0.f);
    acc.z = fmaxf(acc.z + b.z, 0.f); acc.w = fmaxf(acc.w + b.w, 0.f);
    ushort4 o;
    o.x = f2bf(acc.x); o.y = f2bf(acc.y); o.z = f2bf(acc.z); o.w = f2bf(acc.w);
    ((ushort4*)(outh + (size_t)node * 128))[lane] = o;
}

// ---------------- fused final SpMM: out = A@h2 + KAPPA*(A@E) + b2, 4-edge unroll ----------------
__global__ __launch_bounds__(256) void spmm_fused(const unsigned short* __restrict__ big,
                                                  const int* __restrict__ rs,
                                                  const int2* __restrict__ csr,
                                                  const float* __restrict__ b2,
                                                  float* __restrict__ out) {
    int node = blockIdx.x * 4 + (threadIdx.x >> 6);
    int lane = threadIdx.x & 63;
    if (node >= NN) return;
    int e = rs[node];
    const int re = rs[node + 1];
    float4 acc = make_float4(0.f, 0.f, 0.f, 0.f);
    for (; e + 3 < re; e += 4) {
        int2 p0 = csr[e];
        int2 p1 = csr[e + 1];
        int2 p2 = csr[e + 2];
        int2 p3 = csr[e + 3];
        ushort4 v0 = *(const ushort4*)(big + (size_t)p0.x * 256 + lane * 4);
        ushort4 v1 = *(const ushort4*)(big + (size_t)p1.x * 256 + lane * 4);
        ushort4 v2 = *(const ushort4*)(big + (size_t)p2.x * 256 + lane * 4);
        ushort4 v3 = *(const ushort4*)(big + (size_t)p3.x * 256 + lane * 4);
        float w0 = __int_as_float(p0.y), w1 = __int_as_float(p1.y);
        float w2 = __int_as_float(p2.y), w3 = __int_as_float(p3.y);
        acc.x += w0 * bf2f(v0.x) + w1 * bf2f(v1.x) + w2 * bf2f(v2.x) + w3 * bf2f(v3.x);
        acc.y += w0 * bf2f(v0.y) + w1 * bf2f(v1.y) + w2 * bf2f(v2.y) + w3 * bf2f(v3.y);
        acc.z += w0 * bf2f(v0.z) + w1 * bf2f(v1.z) + w2 * bf2f(v2.z) + w3 * bf2f(v3.z);
        acc.w += w0 * bf2f(v0.w) + w1 * bf2f(v1.w) + w2 * bf2f(v2.w) + w3 * bf2f(v3.w);
    }
    for (; e < re; ++e) {
        int2 p0 = csr[e];
        float w0 = __int_as_float(p0.y);
        ushort4 v0 = *(const ushort4*)(big + (size_t)p0.x * 256 + lane * 4);
        acc.x += w0 * bf2f(v0.x); acc.y += w0 * bf2f(v0.y);
        acc.z += w0 * bf2f(v0.z); acc.w += w0 * bf2f(v0.w);
    }
    // lanes 0..31 hold h2-channels; lanes 32..63 hold E-channels of the same node
    int peer = (lane & 31) + 32;
    float ex = __shfl(acc.x, peer);
    float ey = __shfl(acc.y, peer);
    float ez = __shfl(acc.z, peer);
    float ew4 = __shfl(acc.w, peer);
    if (lane < 32) {
        float4 b = ((const float4*)b2)[lane];
        float4 r;
        r.x = acc.x + KAPPA_C * ex + b.x;
        r.y = acc.y + KAPPA_C * ey + b.y;
        r.z = acc.z + KAPPA_C * ez + b.z;
        r.w = acc.w + KAPPA_C * ew4 + b.w;
        ((float4*)(out + (size_t)node * 128))[lane] = r;
    }
}

static inline size_t align_up(size_t x, size_t a) { return (x + a - 1) / a * a; }

extern "C" void kernel_launch(void* const* d_in, const int* in_sizes, int n_in,
                              void* d_out, int out_size, void* d_ws, size_t ws_size,
                              hipStream_t stream) {
    const float* x   = (const float*)d_in[0];
    const int*   esrc = (const int*)d_in[1];
    const int*   edst = (const int*)d_in[2];
    const float* ew  = (const float*)d_in[3];
    const float* W1  = (const float*)d_in[4];
    const float* b1  = (const float*)d_in[5];
    const float* W2  = (const float*)d_in[6];
    const float* b2  = (const float*)d_in[7];
    const float* Fm  = (const float*)d_in[8];
    const float* emb = (const float*)d_in[9];
    float* out = (float*)d_out;

    char* ws = (char*)d_ws;
    size_t off = 0;
    auto alloc = [&](size_t bytes) -> void* {
        void* p = ws + off;
        off = align_up(off + bytes, 256);
        return p;
    };
    unsigned short* B1  = (unsigned short*)alloc((size_t)NN * DD * 2);      // 12.8 MB
    unsigned short* BIG = (unsigned short*)alloc((size_t)NN * 256 * 2);     // 25.6 MB [h2 | E]
    float* Wmat   = (float*)alloc(128 * 128 * 4);
    int*   counts = (int*)alloc((size_t)NN * 4);
    int*   cursor = (int*)alloc((size_t)NN * 4);
    float* ssq    = (float*)alloc(256);
    int*   rs     = (int*)alloc((size_t)(NN + 1) * 4);
    int*   bsum   = (int*)alloc(64 * 4);
    int2*  csr    = (int2*)alloc((size_t)EE * 8);                           // 4.8 MB
    unsigned short* W1th = (unsigned short*)alloc(128 * 128 * 2);
    unsigned short* W1tl = (unsigned short*)alloc(128 * 128 * 2);
    unsigned short* W2th = (unsigned short*)alloc(128 * 128 * 2);
    unsigned short* W2tl = (unsigned short*)alloc(128 * 128 * 2);
    unsigned short* Wmth = (unsigned short*)alloc(128 * 128 * 2);
    unsigned short* Wmtl = (unsigned short*)alloc(128 * 128 * 2);
    if (off > ws_size) return;

    // h scratch lives in d_out (bf16, first 12.8 MB); dead before spmm_fused overwrites out
    unsigned short* H = (unsigned short*)d_out;

    // zero [counts | cursor | ssq]
    size_t zero_bytes = (size_t)((char*)ssq - (char*)counts) + 256;
    hipMemsetAsync(counts, 0, zero_bytes, stream);

    // projection matrix + weight conversions
    wmat_kernel<<<128, 128, 0, stream>>>(Fm, Wmat, ssq);
    wsplit_kernel<<<64, 256, 0, stream>>>(Wmat, ssq, Wmth, Wmtl);
    convm2_kernel<<<128, 256, 0, stream>>>(W1, W2, W1th, W1tl, W2th, W2tl);

    // CSR build (XCD-sliced)
    const int sgrid = NSLICE * FCHUNK;   // 1536
    hist_kernel<<<sgrid, 256, 0, stream>>>(edst, counts);
    scan_blocks<<<NB_SCAN, SCAN_BLK, 0, stream>>>(counts, rs, bsum);
    scan_add<<<NB_SCAN, SCAN_BLK, 0, stream>>>(rs, bsum);
    fill_kernel<<<sgrid, 256, 0, stream>>>(esrc, edst, ew, rs, cursor, csr);

    const int gemm_grid = (NN + 63) / 64;     // 782
    const int spmm_grid1 = (NN + 7) / 8;      // 6250
    const int spmm_gridF = (NN + 3) / 4;      // 12500

    // h1 = bf16(x @ W1) -> B1
    gemm_mfma<true><<<gemm_grid, 256, 0, stream>>>(x, W1th, W1tl, B1, 128, 0, NN);
    // E = bf16(emb @ Wm) -> BIG[:,128:256]
    gemm_mfma<true><<<gemm_grid, 256, 0, stream>>>(emb, Wmth, Wmtl, BIG, 256, 128, NN);
    // h = bf16(relu(A @ h1 + b1)) -> H (in d_out bytes)
    spmm_relu<<<spmm_grid1, 256, 0, stream>>>(B1, rs, csr, b1, H);
    // h2 = bf16(h @ W2) -> BIG[:,0:128]
    gemm_mfma<false><<<gemm_grid, 256, 0, stream>>>(H, W2th, W2tl, BIG, 256, 0, NN);
    // out = A@h2 + KAPPA*(A@E) + b2
    spmm_fused<<<spmm_gridF, 256, 0, stream>>>(BIG, rs, csr, b2, out);
}